// Round 10
// baseline (187.542 us; speedup 1.0000x reference)
//
#include <hip/hip_runtime.h>
#include <stdint.h>

typedef unsigned short u16;
typedef unsigned int   u32;
typedef __attribute__((ext_vector_type(8)))  short short8;
typedef __attribute__((ext_vector_type(2)))  float f32x2;
typedef __attribute__((ext_vector_type(4)))  float f32x4;
typedef __attribute__((ext_vector_type(16))) float f32x16;

#define NTOK 4096
#define LOG2E 1.44269504088896340736f
#define QS    (0.125f * LOG2E)

// round-to-nearest-even f32 -> bf16
__device__ __forceinline__ u16 f2bf(float f) {
    u32 u = __builtin_bit_cast(u32, f);
    u += 0x7fffu + ((u >> 16) & 1u);
    return (u16)(u >> 16);
}
__device__ __forceinline__ float bf2f(u16 v) {
    return __builtin_bit_cast(float, (u32)v << 16);
}
// gfx950 packed f32->bf16 convert (RNE), 1 VALU op: {lo: bf16(a), hi: bf16(b)}
__device__ __forceinline__ u32 cvtpk(float a, float b) {
    u32 r;
    asm("v_cvt_pk_bf16_f32 %0, %1, %2" : "=v"(r) : "v"(a), "v"(b));
    return r;
}
// gfx950 cross-half swap (VALU, no LDS pipe): after call,
// a = {a.lanes0-31, b.lanes0-31}, b = {a.lanes32-63, b.lanes32-63}
__device__ __forceinline__ void pl32swap(u32 &a, u32 &b) {
    asm("v_permlane32_swap_b32 %0, %1" : "+v"(a), "+v"(b));
}
__device__ __forceinline__ f32x16 zero16() {
    f32x16 v;
#pragma unroll
    for (int i = 0; i < 16; ++i) v[i] = 0.f;
    return v;
}

#define MFMA16x32 __builtin_amdgcn_mfma_f32_16x16x32_bf16
#define MFMA32x16 __builtin_amdgcn_mfma_f32_32x32x16_bf16

// ---------------- kernel 1: QKV projection via MFMA (frozen from R12) ----------------
// K and V stored FRAG-PACKED: every attn fragment load is a contiguous 1KB
// wave load (16 L2 line-requests, minimum) -- R12 proved this is worth 1.3x.
__global__ __launch_bounds__(256) void qkv_mfma5(
    const float* __restrict__ x,
    const float* __restrict__ wq, const float* __restrict__ bq,
    const float* __restrict__ wk, const float* __restrict__ bk,
    const float* __restrict__ wv, const float* __restrict__ bv,
    u16* __restrict__ Q, u16* __restrict__ KF, u16* __restrict__ VF)
{
    __shared__ __align__(16) u16 Wl[3 * 64 * 72];
    __shared__ __align__(16) u16 Xl[64 * 64];
    const int tid  = threadIdx.x;
    const int b    = blockIdx.x & 7;
    const int slab = blockIdx.x >> 3;
    const int n0   = slab << 6;
    const int wave = tid >> 6;
    const int lane = tid & 63;
    const int quad = lane >> 4;
    const int l15  = lane & 15;

#pragma unroll
    for (int j = 0; j < 12; ++j) {
        const float* src = (j < 4) ? wq : (j < 8) ? wk : wv;
        const float sc = (j < 4) ? QS : 1.0f;
        const int idx = (j & 3) * 1024 + tid * 4;
        const float4 v = *(const float4*)(src + idx);
        uint2 pk;
        pk.x = (u32)f2bf(v.x * sc) | ((u32)f2bf(v.y * sc) << 16);
        pk.y = (u32)f2bf(v.z * sc) | ((u32)f2bf(v.w * sc) << 16);
        *(uint2*)&Wl[(j >> 2) * 4608 + (idx >> 6) * 72 + (idx & 63)] = pk;
    }

    float4 xs[4];
#pragma unroll
    for (int g = 0; g < 4; ++g) {
        const int ch = g * 16 + wave * 4 + quad;
        xs[g] = *(const float4*)(x + ((size_t)(b * 64 + ch)) * NTOK + n0 + l15 * 4);
    }
#pragma unroll
    for (int g = 0; g < 4; ++g) {
        const int ch = g * 16 + wave * 4 + quad;
        const float vv[4] = {xs[g].x, xs[g].y, xs[g].z, xs[g].w};
#pragma unroll
        for (int e = 0; e < 4; ++e) {
            const int tok = l15 * 4 + e;
            Xl[tok * 64 + (((ch >> 3) ^ (tok & 7)) & 7) * 8 + (ch & 7)] = f2bf(vv[e]);
        }
    }
    __syncthreads();

    const int row0 = wave * 16 + l15;
    short8 xf[2];
#pragma unroll
    for (int kk = 0; kk < 2; ++kk)
        xf[kk] = *(const short8*)&Xl[row0 * 64 + (((kk * 4 + quad) ^ (row0 & 7)) & 7) * 8];

    const size_t tokbase = (size_t)b * NTOK + n0 + wave * 16;

#pragma unroll
    for (int mat = 0; mat < 2; ++mat) {
        const float* bias = (mat == 0) ? bq : bk;
        const float bsc = (mat == 0) ? QS : 1.0f;
#pragma unroll
        for (int mt = 0; mt < 4; ++mt) {
            const u16* wr = &Wl[mat * 4608 + (mt * 16 + l15) * 72 + quad * 8];
            const short8 wf0 = *(const short8*)(wr);
            const short8 wf1 = *(const short8*)(wr + 32);
            f32x4 acc = {0.f, 0.f, 0.f, 0.f};
            acc = MFMA16x32(wf0, xf[0], acc, 0, 0, 0);
            acc = MFMA16x32(wf1, xf[1], acc, 0, 0, 0);
            const float4 b4 = *(const float4*)(bias + mt * 16 + quad * 4);
            uint2 pk;
            pk.x = (u32)f2bf(acc[0] + b4.x * bsc) | ((u32)f2bf(acc[1] + b4.y * bsc) << 16);
            pk.y = (u32)f2bf(acc[2] + b4.z * bsc) | ((u32)f2bf(acc[3] + b4.w * bsc) << 16);
            if (mat == 0) {
                *(uint2*)(Q + (tokbase + l15) * 64 + mt * 16 + quad * 4) = pk;
            } else {
                const int tokl = wave * 16 + l15;
                const int gt   = slab * 2 + (tokl >> 5);
                const int c31k = tokl & 31;
                const int hwk  = quad >> 1;
                const int j0   = (quad & 1) * 4;
                *(uint2*)(KF + (((size_t)b * 128 + gt) * 4 + mt) * 512
                             + (hwk * 32 + c31k) * 8 + j0) = pk;
            }
        }
    }

    __syncthreads();
    u16* Vl = Xl;
    const int tok = wave * 16 + l15;
#pragma unroll
    for (int mt = 0; mt < 4; ++mt) {
        const u16* wr = &Wl[2 * 4608 + (mt * 16 + l15) * 72 + quad * 8];
        const short8 wf0 = *(const short8*)(wr);
        const short8 wf1 = *(const short8*)(wr + 32);
        f32x4 acc = {0.f, 0.f, 0.f, 0.f};
        acc = MFMA16x32(wf0, xf[0], acc, 0, 0, 0);
        acc = MFMA16x32(wf1, xf[1], acc, 0, 0, 0);
        const float4 b4 = *(const float4*)(bv + mt * 16 + quad * 4);
        const float o[4] = {acc[0] + b4.x, acc[1] + b4.y, acc[2] + b4.z, acc[3] + b4.w};
#pragma unroll
        for (int r = 0; r < 4; ++r) {
            const int d = mt * 16 + quad * 4 + r;
            Vl[d * 64 + (((tok >> 3) ^ ((d >> 1) & 7)) & 7) * 8 + (tok & 7)] = f2bf(o[r]);
        }
    }
    __syncthreads();

#pragma unroll
    for (int dd = 0; dd < 4; ++dd) {
        const int d2   = (tid >> 4) + dd * 16;
        const int tok0 = (tid & 15) * 4;
        const int slot = ((tok0 >> 3) ^ ((d2 >> 1) & 7)) & 7;
        const uint2 v2 = *(const uint2*)&Vl[d2 * 64 + slot * 8 + (tok0 & 7)];
        const int gt  = slab * 2 + (tok0 >> 5);
        const int mk  = ((d2 >> 5) << 1) | ((tok0 & 31) >> 4);
        const int hwv = (tok0 >> 3) & 1;
        const int j   = tok0 & 7;
        *(uint2*)(VF + (((size_t)b * 128 + gt) * 4 + mk) * 512
                     + (hwv * 32 + (d2 & 31)) * 8 + j) = v2;
    }
}

// ---------------- kernel 2: fused attention + mix + 2x2 pool ----------------
// R17 = R13's per-wave structure (single sv, 2-deep dbuf, cvtpk/pl32swap tail
// -- the only variant measured at 168 total regs) widened to a 12-WAVE block:
// 768 thr = 2 Q-halves x 6 KV slices (22/22/22/22/20/20 tiles of 32 tok).
// __launch_bounds__(768,3) -> 3 waves/SIMD (cap 170; 168x3=504<=512 fits).
// Rationale: R14 vs R16 -- two different in-wave schedules, identical 49.4us
// and counters -> in-wave ILP is saturated; the ~36% idle issue needs MORE
// WAVES. Each slice still read by exactly 2 waves (h=0,1) so L2 requests per
// block unchanged (the R9 mistake avoided). LDS 90112B: 10 sections (h*5+s-1)
// 64x68 bf16 + lp[12][64] f32; M0/Mf overlay the dead section region after B3.
// Marker: VGPR ~104-106 + FETCH ~6.3MB (explosion = spill -> revert).
__global__ __launch_bounds__(768, 3) void attn17(
    const u16* __restrict__ Q, const u16* __restrict__ KF,
    const u16* __restrict__ VF,
    const float* __restrict__ wm, const float* __restrict__ bm,
    float* __restrict__ out)
{
    // LDS: sections [0,87040) = 10 x (64x68 bf16, 8704B) | lp [87040,90112) 12x64 f32
    // overlay after B3: M0 [0,16384) bf16[128][64] swz; Mf [16384,51200) f32[128][68]
    __shared__ __align__(16) char smem[90112];
    const int tid  = threadIdx.x;
    const int wave = tid >> 6;
    const int lane = tid & 63;
    const int c31  = lane & 31;
    const int hw   = lane >> 5;          // half-wave
    const int quad = lane >> 4;
    const int l15  = lane & 15;
    const int h    = wave / 6;           // Q half (64 rows)
    const int s    = wave - h * 6;       // KV slice (0..5)
    const int b    = blockIdx.x & 7;
    const int oh   = blockIdx.x >> 3;
    const int n0   = oh * 128;

    // slice geometry: tiles of 32 tokens; counts 22,22,22,22,20,20 (all even)
    const int start = (s < 4) ? s * 22 : 88 + (s - 4) * 20;
    const int cnt   = (s < 4) ? 22 : 20;

    // Q B-frags: B[k=ch][n=qrow]: lane (c31,hw) reads Q[qrow=nt*32+c31][ks*16+hw*8+j]
    short8 qf[2][4];
#pragma unroll
    for (int nt = 0; nt < 2; ++nt)
#pragma unroll
        for (int ks = 0; ks < 4; ++ks)
            qf[nt][ks] = *(const short8*)(Q + ((size_t)(b * NTOK + n0 + h * 64 + nt * 32 + c31)) * 64
                                            + ks * 16 + hw * 8);

    const u16* KFb = KF + ((size_t)b * 128 + start) * 2048;
    const u16* VFb = VF + ((size_t)b * 128 + start) * 2048;
    const int l8 = lane * 8;             // u16 offset of this lane's 16B frag chunk

    f32x16 O[2][2];                       // [mt][nt] = O^T tiles, 64 acc regs
#pragma unroll
    for (int mt = 0; mt < 2; ++mt)
#pragma unroll
        for (int nt = 0; nt < 2; ++nt) O[mt][nt] = zero16();
    float lpa[2] = {0.f, 0.f};

    auto load_kv = [&](short8 (&kf)[4], short8 (&vf)[4], int t) {
        const int tc = (t < cnt) ? t : cnt - 1;    // clamp: last prefetch in-bounds
        const u16* kt = KFb + (size_t)tc * 2048;
#pragma unroll
        for (int ks = 0; ks < 4; ++ks)
            kf[ks] = *(const short8*)(kt + ks * 512 + l8);
        const u16* vt = VFb + (size_t)tc * 2048;
#pragma unroll
        for (int mk = 0; mk < 4; ++mk)
            vf[mk] = *(const short8*)(vt + mk * 512 + l8);
    };

    auto tile_tail = [&](const f32x16 (&sv)[2], const short8 (&vf)[4]) {
#pragma unroll
        for (int nt = 0; nt < 2; ++nt) {
            float p[16];
#pragma unroll
            for (int r = 0; r < 16; ++r) p[r] = __builtin_amdgcn_exp2f(sv[nt][r]);
            // lp: f32x2 pairwise tree (v_pk_add_f32)
            const f32x2 a0 = {p[0],  p[1]},  a1 = {p[2],  p[3]};
            const f32x2 a2 = {p[4],  p[5]},  a3 = {p[6],  p[7]};
            const f32x2 a4 = {p[8],  p[9]},  a5 = {p[10], p[11]};
            const f32x2 a6 = {p[12], p[13]}, a7 = {p[14], p[15]};
            const f32x2 s0 = a0 + a1, s1 = a2 + a3, s2 = a4 + a5, s3 = a6 + a7;
            const f32x2 s4 = s0 + s1, s5 = s2 + s3;
            const f32x2 s6 = s4 + s5;
            lpa[nt] += s6.x + s6.y;
            u32 c0 = cvtpk(p[0],  p[1]),  c1 = cvtpk(p[2],  p[3]);
            u32 c2 = cvtpk(p[4],  p[5]),  c3 = cvtpk(p[6],  p[7]);
            u32 c4 = cvtpk(p[8],  p[9]),  c5 = cvtpk(p[10], p[11]);
            u32 c6 = cvtpk(p[12], p[13]), c7 = cvtpk(p[14], p[15]);
            // cross-half exchange fully in VALU
            pl32swap(c0, c2);  pl32swap(c1, c3);
            pl32swap(c4, c6);  pl32swap(c5, c7);
            uint4 B0, B1;                 // P^T B-frags, k-windows 0-15 / 16-31
            B0.x = c0; B0.y = c1; B0.z = c2; B0.w = c3;
            B1.x = c4; B1.y = c5; B1.z = c6; B1.w = c7;
            const short8 pb0 = __builtin_bit_cast(short8, B0);
            const short8 pb1 = __builtin_bit_cast(short8, B1);
            __builtin_amdgcn_s_setprio(1);
            O[0][nt] = MFMA32x16(vf[0], pb0, O[0][nt], 0, 0, 0);
            O[0][nt] = MFMA32x16(vf[1], pb1, O[0][nt], 0, 0, 0);
            O[1][nt] = MFMA32x16(vf[2], pb0, O[1][nt], 0, 0, 0);
            O[1][nt] = MFMA32x16(vf[3], pb1, O[1][nt], 0, 0, 0);
            __builtin_amdgcn_s_setprio(0);
        }
    };

    short8 kfA[4], vfA[4], kfB[4], vfB[4];
    load_kv(kfA, vfA, 0);

    const int half = cnt >> 1;            // 11 or 10
#pragma unroll 1
    for (int tt = 0; tt < half; ++tt) {
        const int t0 = tt * 2;
        f32x16 sv0[2];
        __builtin_amdgcn_s_setprio(1);
#pragma unroll
        for (int nt = 0; nt < 2; ++nt) {
            f32x16 a = zero16();
            a = MFMA32x16(kfA[0], qf[nt][0], a, 0, 0, 0);
            a = MFMA32x16(kfA[1], qf[nt][1], a, 0, 0, 0);
            a = MFMA32x16(kfA[2], qf[nt][2], a, 0, 0, 0);
            a = MFMA32x16(kfA[3], qf[nt][3], a, 0, 0, 0);
            sv0[nt] = a;
        }
        __builtin_amdgcn_s_setprio(0);
        load_kv(kfB, vfB, t0 + 1);        // prefetch overlaps exp2/swap/PV
        tile_tail(sv0, vfA);

        f32x16 sv1[2];
        __builtin_amdgcn_s_setprio(1);
#pragma unroll
        for (int nt = 0; nt < 2; ++nt) {
            f32x16 a = zero16();
            a = MFMA32x16(kfB[0], qf[nt][0], a, 0, 0, 0);
            a = MFMA32x16(kfB[1], qf[nt][1], a, 0, 0, 0);
            a = MFMA32x16(kfB[2], qf[nt][2], a, 0, 0, 0);
            a = MFMA32x16(kfB[3], qf[nt][3], a, 0, 0, 0);
            sv1[nt] = a;
        }
        __builtin_amdgcn_s_setprio(0);
        load_kv(kfA, vfA, t0 + 2);        // clamped at end (values unused)
        tile_tail(sv1, vfB);
    }

    // ---- epilogue ----
    // combine lp halves (disjoint token sets), lane (c31,*) -> lp[qrow nt*32+c31]
#pragma unroll
    for (int nt = 0; nt < 2; ++nt) lpa[nt] += __shfl_xor(lpa[nt], 32);

    float* lpbuf = (float*)(smem + 87040);
    if (hw == 0) {
#pragma unroll
        for (int nt = 0; nt < 2; ++nt)
            lpbuf[(h * 6 + s) * 64 + nt * 32 + c31] = lpa[nt];
    }
    if (s != 0) {                          // bf16 O-partial sections
        u16* sec = (u16*)smem + (h * 5 + s - 1) * 4352;
#pragma unroll
        for (int mt = 0; mt < 2; ++mt)
#pragma unroll
            for (int nt = 0; nt < 2; ++nt)
#pragma unroll
                for (int r = 0; r < 16; ++r) {
                    const int ch = mt * 32 + (r & 3) + 8 * (r >> 2) + 4 * hw;
                    sec[(nt * 32 + c31) * 68 + ch] = f2bf(O[mt][nt][r]);
                }
    }
    __syncthreads();   // B2: all partials visible

    float rinv[2];
    if (s == 0) {
#pragma unroll
        for (int nt = 0; nt < 2; ++nt) {
            float sum = 0.f;
#pragma unroll
            for (int sx = 0; sx < 6; ++sx)
                sum += lpbuf[(h * 6 + sx) * 64 + nt * 32 + c31];
            rinv[nt] = 1.0f / sum;
        }
#pragma unroll 1
        for (int sx = 1; sx < 6; ++sx) {
            const u16* sec = (const u16*)smem + (h * 5 + sx - 1) * 4352;
#pragma unroll
            for (int mt = 0; mt < 2; ++mt)
#pragma unroll
                for (int nt = 0; nt < 2; ++nt)
#pragma unroll
                    for (int r = 0; r < 16; ++r) {
                        const int ch = mt * 32 + (r & 3) + 8 * (r >> 2) + 4 * hw;
                        O[mt][nt][r] += bf2f(sec[(nt * 32 + c31) * 68 + ch]);
                    }
        }
    }
    // waves 0-7: convert wm -> bf16 B-frags + bias (overlaps the s==0 reduction)
    short8 wB[4][2];
    float bb[4];
    if (wave < 8) {
#pragma unroll
        for (int nt = 0; nt < 4; ++nt) {
            const int d = nt * 16 + l15;
            const float* wr = wm + (size_t)d * 64 + quad * 8;
            const float4 a0 = *(const float4*)(wr);
            const float4 a1 = *(const float4*)(wr + 4);
            const float4 c0 = *(const float4*)(wr + 32);
            const float4 c1 = *(const float4*)(wr + 36);
            ((u32*)&wB[nt][0])[0] = (u32)f2bf(a0.x) | ((u32)f2bf(a0.y) << 16);
            ((u32*)&wB[nt][0])[1] = (u32)f2bf(a0.z) | ((u32)f2bf(a0.w) << 16);
            ((u32*)&wB[nt][0])[2] = (u32)f2bf(a1.x) | ((u32)f2bf(a1.y) << 16);
            ((u32*)&wB[nt][0])[3] = (u32)f2bf(a1.z) | ((u32)f2bf(a1.w) << 16);
            ((u32*)&wB[nt][1])[0] = (u32)f2bf(c0.x) | ((u32)f2bf(c0.y) << 16);
            ((u32*)&wB[nt][1])[1] = (u32)f2bf(c0.z) | ((u32)f2bf(c0.w) << 16);
            ((u32*)&wB[nt][1])[2] = (u32)f2bf(c1.x) | ((u32)f2bf(c1.y) << 16);
            ((u32*)&wB[nt][1])[3] = (u32)f2bf(c1.z) | ((u32)f2bf(c1.w) << 16);
            bb[nt] = bm[d];
        }
    }
    __syncthreads();   // B3: section/lp reads done; M0 may overlay

    if (s == 0) {      // normalize -> M0 bf16 (swizzled [qrow][ch]) at h*8KB
        u16* M0 = (u16*)smem + h * 4096;
#pragma unroll
        for (int mt = 0; mt < 2; ++mt)
#pragma unroll
            for (int nt = 0; nt < 2; ++nt)
#pragma unroll
                for (int r = 0; r < 16; ++r) {
                    const int lr = nt * 32 + c31;
                    const int ch = mt * 32 + (r & 3) + 8 * (r >> 2) + 4 * hw;
                    const float v = O[mt][nt][r] * rinv[nt];
                    M0[lr * 64 + (((ch >> 3) ^ (lr & 7)) & 7) * 8 + (ch & 7)] = f2bf(v);
                }
    }
    __syncthreads();   // B4: M0 complete

    // mix: wave w<8 handles rows [16w, 16w+16) (R7-proven mapping)
    if (wave < 8) {
        const u16* M0r = (const u16*)smem + (wave >> 2) * 4096;
        const int lr = (wave & 3) * 16 + l15;
        const short8 af0 = *(const short8*)&M0r[lr * 64 + ((quad ^ (lr & 7)) & 7) * 8];
        const short8 af1 = *(const short8*)&M0r[lr * 64 + (((4 + quad) ^ (lr & 7)) & 7) * 8];
        float* Mf = (float*)(smem + 16384);      // [128][68] fp32, disjoint from M0
#pragma unroll
        for (int nt = 0; nt < 4; ++nt) {
            f32x4 acc = {0.f, 0.f, 0.f, 0.f};
            acc = MFMA16x32(af0, wB[nt][0], acc, 0, 0, 0);
            acc = MFMA16x32(af1, wB[nt][1], acc, 0, 0, 0);
#pragma unroll
            for (int r = 0; r < 4; ++r) {
                float v = acc[r] + bb[nt];
                v = v > 0.f ? v : 0.f;
                Mf[(wave * 16 + quad * 4 + r) * 68 + nt * 16 + l15] = v;
            }
        }
    }
    __syncthreads();   // B5

    // 2x2 avg pool (== bilinear 2x downsample, half-pixel); threads 0-511, 4 ch
    if (tid < 512) {
        const float* Mf = (const float*)(smem + 16384);
        const int ow = tid & 31;
        const int cb = (tid >> 5) & 15;
#pragma unroll
        for (int i = 0; i < 4; ++i) {
            const int c = cb + i * 16;
            const float v = 0.25f * (Mf[(2 * ow) * 68 + c] + Mf[(2 * ow + 1) * 68 + c]
                                   + Mf[(64 + 2 * ow) * 68 + c] + Mf[(65 + 2 * ow) * 68 + c]);
            out[((size_t)(b * 64 + c) * 32 + oh) * 32 + ow] = v;
        }
    }
}

extern "C" void kernel_launch(void* const* d_in, const int* in_sizes, int n_in,
                              void* d_out, int out_size, void* d_ws, size_t ws_size,
                              hipStream_t stream) {
    (void)in_sizes; (void)n_in; (void)out_size; (void)ws_size;
    const float* x  = (const float*)d_in[0];
    const float* wq = (const float*)d_in[1];
    const float* bq = (const float*)d_in[2];
    const float* wk = (const float*)d_in[3];
    const float* bk = (const float*)d_in[4];
    const float* wv = (const float*)d_in[5];
    const float* bv = (const float*)d_in[6];
    const float* wm = (const float*)d_in[7];
    const float* bm = (const float*)d_in[8];

    // ws: Q bf16 [8][4096][64] | KF bf16 [8][128][4][512] | VF bf16 [8][128][4][512] = 12 MB
    u16* Q  = (u16*)d_ws;
    u16* KF = Q + (size_t)8 * NTOK * 64;
    u16* VF = KF + (size_t)8 * NTOK * 64;

    qkv_mfma5<<<512, 256, 0, stream>>>(x, wq, bq, wk, bk, wv, bv, Q, KF, VF);
    attn17<<<256, 768, 0, stream>>>(Q, KF, VF, wm, bm, (float*)d_out);
}

// Round 12
// 124.917 us; speedup vs baseline: 1.5013x; 1.5013x over previous
//
#include <hip/hip_runtime.h>
#include <stdint.h>

typedef unsigned short u16;
typedef unsigned int   u32;
typedef __attribute__((ext_vector_type(8)))  short short8;
typedef __attribute__((ext_vector_type(2)))  float f32x2;
typedef __attribute__((ext_vector_type(4)))  float f32x4;
typedef __attribute__((ext_vector_type(16))) float f32x16;

#define NTOK 4096
#define LOG2E 1.44269504088896340736f
#define QS    (0.125f * LOG2E)

// round-to-nearest-even f32 -> bf16
__device__ __forceinline__ u16 f2bf(float f) {
    u32 u = __builtin_bit_cast(u32, f);
    u += 0x7fffu + ((u >> 16) & 1u);
    return (u16)(u >> 16);
}
__device__ __forceinline__ float bf2f(u16 v) {
    return __builtin_bit_cast(float, (u32)v << 16);
}
// gfx950 packed f32->bf16 convert (RNE), 1 VALU op: {lo: bf16(a), hi: bf16(b)}
__device__ __forceinline__ u32 cvtpk(float a, float b) {
    u32 r;
    asm("v_cvt_pk_bf16_f32 %0, %1, %2" : "=v"(r) : "v"(a), "v"(b));
    return r;
}
// gfx950 cross-half swap (VALU, no LDS pipe): after call,
// a = {a.lanes0-31, b.lanes0-31}, b = {a.lanes32-63, b.lanes32-63}
__device__ __forceinline__ void pl32swap(u32 &a, u32 &b) {
    asm("v_permlane32_swap_b32 %0, %1" : "+v"(a), "+v"(b));
}
__device__ __forceinline__ f32x16 zero16() {
    f32x16 v;
#pragma unroll
    for (int i = 0; i < 16; ++i) v[i] = 0.f;
    return v;
}

#define MFMA16x32 __builtin_amdgcn_mfma_f32_16x16x32_bf16
#define MFMA32x16 __builtin_amdgcn_mfma_f32_32x32x16_bf16

// ---------------- kernel 1: QKV projection via MFMA (frozen from R12) ----------------
// K and V stored FRAG-PACKED: every attn fragment load is a contiguous 1KB
// wave load (16 L2 line-requests, minimum) -- R12 proved this is worth 1.3x.
__global__ __launch_bounds__(256) void qkv_mfma5(
    const float* __restrict__ x,
    const float* __restrict__ wq, const float* __restrict__ bq,
    const float* __restrict__ wk, const float* __restrict__ bk,
    const float* __restrict__ wv, const float* __restrict__ bv,
    u16* __restrict__ Q, u16* __restrict__ KF, u16* __restrict__ VF)
{
    __shared__ __align__(16) u16 Wl[3 * 64 * 72];
    __shared__ __align__(16) u16 Xl[64 * 64];
    const int tid  = threadIdx.x;
    const int b    = blockIdx.x & 7;
    const int slab = blockIdx.x >> 3;
    const int n0   = slab << 6;
    const int wave = tid >> 6;
    const int lane = tid & 63;
    const int quad = lane >> 4;
    const int l15  = lane & 15;

#pragma unroll
    for (int j = 0; j < 12; ++j) {
        const float* src = (j < 4) ? wq : (j < 8) ? wk : wv;
        const float sc = (j < 4) ? QS : 1.0f;
        const int idx = (j & 3) * 1024 + tid * 4;
        const float4 v = *(const float4*)(src + idx);
        uint2 pk;
        pk.x = (u32)f2bf(v.x * sc) | ((u32)f2bf(v.y * sc) << 16);
        pk.y = (u32)f2bf(v.z * sc) | ((u32)f2bf(v.w * sc) << 16);
        *(uint2*)&Wl[(j >> 2) * 4608 + (idx >> 6) * 72 + (idx & 63)] = pk;
    }

    float4 xs[4];
#pragma unroll
    for (int g = 0; g < 4; ++g) {
        const int ch = g * 16 + wave * 4 + quad;
        xs[g] = *(const float4*)(x + ((size_t)(b * 64 + ch)) * NTOK + n0 + l15 * 4);
    }
#pragma unroll
    for (int g = 0; g < 4; ++g) {
        const int ch = g * 16 + wave * 4 + quad;
        const float vv[4] = {xs[g].x, xs[g].y, xs[g].z, xs[g].w};
#pragma unroll
        for (int e = 0; e < 4; ++e) {
            const int tok = l15 * 4 + e;
            Xl[tok * 64 + (((ch >> 3) ^ (tok & 7)) & 7) * 8 + (ch & 7)] = f2bf(vv[e]);
        }
    }
    __syncthreads();

    const int row0 = wave * 16 + l15;
    short8 xf[2];
#pragma unroll
    for (int kk = 0; kk < 2; ++kk)
        xf[kk] = *(const short8*)&Xl[row0 * 64 + (((kk * 4 + quad) ^ (row0 & 7)) & 7) * 8];

    const size_t tokbase = (size_t)b * NTOK + n0 + wave * 16;

#pragma unroll
    for (int mat = 0; mat < 2; ++mat) {
        const float* bias = (mat == 0) ? bq : bk;
        const float bsc = (mat == 0) ? QS : 1.0f;
#pragma unroll
        for (int mt = 0; mt < 4; ++mt) {
            const u16* wr = &Wl[mat * 4608 + (mt * 16 + l15) * 72 + quad * 8];
            const short8 wf0 = *(const short8*)(wr);
            const short8 wf1 = *(const short8*)(wr + 32);
            f32x4 acc = {0.f, 0.f, 0.f, 0.f};
            acc = MFMA16x32(wf0, xf[0], acc, 0, 0, 0);
            acc = MFMA16x32(wf1, xf[1], acc, 0, 0, 0);
            const float4 b4 = *(const float4*)(bias + mt * 16 + quad * 4);
            uint2 pk;
            pk.x = (u32)f2bf(acc[0] + b4.x * bsc) | ((u32)f2bf(acc[1] + b4.y * bsc) << 16);
            pk.y = (u32)f2bf(acc[2] + b4.z * bsc) | ((u32)f2bf(acc[3] + b4.w * bsc) << 16);
            if (mat == 0) {
                *(uint2*)(Q + (tokbase + l15) * 64 + mt * 16 + quad * 4) = pk;
            } else {
                const int tokl = wave * 16 + l15;
                const int gt   = slab * 2 + (tokl >> 5);
                const int c31k = tokl & 31;
                const int hwk  = quad >> 1;
                const int j0   = (quad & 1) * 4;
                *(uint2*)(KF + (((size_t)b * 128 + gt) * 4 + mt) * 512
                             + (hwk * 32 + c31k) * 8 + j0) = pk;
            }
        }
    }

    __syncthreads();
    u16* Vl = Xl;
    const int tok = wave * 16 + l15;
#pragma unroll
    for (int mt = 0; mt < 4; ++mt) {
        const u16* wr = &Wl[2 * 4608 + (mt * 16 + l15) * 72 + quad * 8];
        const short8 wf0 = *(const short8*)(wr);
        const short8 wf1 = *(const short8*)(wr + 32);
        f32x4 acc = {0.f, 0.f, 0.f, 0.f};
        acc = MFMA16x32(wf0, xf[0], acc, 0, 0, 0);
        acc = MFMA16x32(wf1, xf[1], acc, 0, 0, 0);
        const float4 b4 = *(const float4*)(bv + mt * 16 + quad * 4);
        const float o[4] = {acc[0] + b4.x, acc[1] + b4.y, acc[2] + b4.z, acc[3] + b4.w};
#pragma unroll
        for (int r = 0; r < 4; ++r) {
            const int d = mt * 16 + quad * 4 + r;
            Vl[d * 64 + (((tok >> 3) ^ ((d >> 1) & 7)) & 7) * 8 + (tok & 7)] = f2bf(o[r]);
        }
    }
    __syncthreads();

#pragma unroll
    for (int dd = 0; dd < 4; ++dd) {
        const int d2   = (tid >> 4) + dd * 16;
        const int tok0 = (tid & 15) * 4;
        const int slot = ((tok0 >> 3) ^ ((d2 >> 1) & 7)) & 7;
        const uint2 v2 = *(const uint2*)&Vl[d2 * 64 + slot * 8 + (tok0 & 7)];
        const int gt  = slab * 2 + (tok0 >> 5);
        const int mk  = ((d2 >> 5) << 1) | ((tok0 & 31) >> 4);
        const int hwv = (tok0 >> 3) & 1;
        const int j   = tok0 & 7;
        *(uint2*)(VF + (((size_t)b * 128 + gt) * 4 + mk) * 512
                     + (hwv * 32 + (d2 & 31)) * 8 + j) = v2;
    }
}

// ---------------- kernel 2: fused attention + mix + 2x2 pool ----------------
// R18 RETEST (previous failure was harness-level: "MI355X container failed
// twice", raised before pytest; kernel audit shows no hang mechanism).
// Design: 3 waves/SIMD, register-budgeted to ~144 (R17's 168 spilled; the
// effective cap at (768,3) is ~160). 12 waves = 2 Q-halves x 6 KV slices
// (22/22/22/22/20/20 tiles). SINGLE-buffered K and V (32 regs vs 64): K
// reloaded right after its last QK (slack ~= one tail, ~400cy), V right
// after its last PV (slack ~= QK+exp, ~300cy), pinned with sched_barrier(0).
// R9's version collapsed, but R9 had unpacked layouts (2x L2 requests --
// fixed by R12 frag-packing), 4-way qg sharing (2x traffic -- now 2-way h),
// and just-in-time loads. Per-nt tail (R16-proven equal). Epilogue = R17.
// Markers: VGPR ~80-92 arch AND FETCH ~6.3MB = buffers live, no spill;
// FETCH explosion = spill (revert R14); MfmaUtil<20 = latency exposure.
__global__ __launch_bounds__(768, 3) void attn18(
    const u16* __restrict__ Q, const u16* __restrict__ KF,
    const u16* __restrict__ VF,
    const float* __restrict__ wm, const float* __restrict__ bm,
    float* __restrict__ out)
{
    // LDS: sections [0,87040) = 10 x (64x68 bf16, 8704B) | lp [87040,90112) 12x64 f32
    // overlay after B3: M0 [0,16384) bf16[128][64] swz; Mf [16384,51200) f32[128][68]
    __shared__ __align__(16) char smem[90112];
    const int tid  = threadIdx.x;
    const int wave = tid >> 6;
    const int lane = tid & 63;
    const int c31  = lane & 31;
    const int hw   = lane >> 5;          // half-wave
    const int quad = lane >> 4;
    const int l15  = lane & 15;
    const int h    = wave / 6;           // Q half (64 rows)
    const int s    = wave - h * 6;       // KV slice (0..5)
    const int b    = blockIdx.x & 7;
    const int oh   = blockIdx.x >> 3;
    const int n0   = oh * 128;

    // slice geometry: tiles of 32 tokens; counts 22,22,22,22,20,20
    const int start = (s < 4) ? s * 22 : 88 + (s - 4) * 20;
    const int cnt   = (s < 4) ? 22 : 20;

    // Q B-frags: B[k=ch][n=qrow]: lane (c31,hw) reads Q[qrow=nt*32+c31][ks*16+hw*8+j]
    short8 qf[2][4];
#pragma unroll
    for (int nt = 0; nt < 2; ++nt)
#pragma unroll
        for (int ks = 0; ks < 4; ++ks)
            qf[nt][ks] = *(const short8*)(Q + ((size_t)(b * NTOK + n0 + h * 64 + nt * 32 + c31)) * 64
                                            + ks * 16 + hw * 8);

    const u16* KFb = KF + ((size_t)b * 128 + start) * 2048;
    const u16* VFb = VF + ((size_t)b * 128 + start) * 2048;
    const int l8 = lane * 8;             // u16 offset of this lane's 16B frag chunk

    f32x16 O[2][2];                       // [mt][nt] = O^T tiles, 64 acc regs
#pragma unroll
    for (int mt = 0; mt < 2; ++mt)
#pragma unroll
        for (int nt = 0; nt < 2; ++nt) O[mt][nt] = zero16();
    float lpa[2] = {0.f, 0.f};

    auto load_k = [&](short8 (&kf)[4], int t) {
        const int tc = (t < cnt) ? t : cnt - 1;    // clamp: last prefetch in-bounds
        const u16* kt = KFb + (size_t)tc * 2048;
#pragma unroll
        for (int ks = 0; ks < 4; ++ks)
            kf[ks] = *(const short8*)(kt + ks * 512 + l8);
    };
    auto load_v = [&](short8 (&vf)[4], int t) {
        const int tc = (t < cnt) ? t : cnt - 1;
        const u16* vt = VFb + (size_t)tc * 2048;
#pragma unroll
        for (int mk = 0; mk < 4; ++mk)
            vf[mk] = *(const short8*)(vt + mk * 512 + l8);
    };

    // QK for one nt sub-tile: sv <- K(tile)^T Q[nt]  (4 MFMA)
    auto qk_nt = [&](f32x16 &sv, const short8 (&kf)[4], const short8 (&q)[4]) {
        __builtin_amdgcn_s_setprio(1);
        f32x16 a = zero16();
        a = MFMA32x16(kf[0], q[0], a, 0, 0, 0);
        a = MFMA32x16(kf[1], q[1], a, 0, 0, 0);
        a = MFMA32x16(kf[2], q[2], a, 0, 0, 0);
        a = MFMA32x16(kf[3], q[3], a, 0, 0, 0);
        sv = a;
        __builtin_amdgcn_s_setprio(0);
    };

    // softmax tail + PV for one nt sub-tile
    auto tail_nt = [&](const f32x16 &sv, const short8 (&vf)[4],
                       float &lp, f32x16 &O0, f32x16 &O1) {
        float p[16];
#pragma unroll
        for (int r = 0; r < 16; ++r) p[r] = __builtin_amdgcn_exp2f(sv[r]);
        const f32x2 a0 = {p[0],  p[1]},  a1 = {p[2],  p[3]};
        const f32x2 a2 = {p[4],  p[5]},  a3 = {p[6],  p[7]};
        const f32x2 a4 = {p[8],  p[9]},  a5 = {p[10], p[11]};
        const f32x2 a6 = {p[12], p[13]}, a7 = {p[14], p[15]};
        const f32x2 s0 = a0 + a1, s1 = a2 + a3, s2 = a4 + a5, s3 = a6 + a7;
        const f32x2 s4 = s0 + s1, s5 = s2 + s3;
        const f32x2 s6 = s4 + s5;
        lp += s6.x + s6.y;
        u32 c0 = cvtpk(p[0],  p[1]),  c1 = cvtpk(p[2],  p[3]);
        u32 c2 = cvtpk(p[4],  p[5]),  c3 = cvtpk(p[6],  p[7]);
        u32 c4 = cvtpk(p[8],  p[9]),  c5 = cvtpk(p[10], p[11]);
        u32 c6 = cvtpk(p[12], p[13]), c7 = cvtpk(p[14], p[15]);
        pl32swap(c0, c2);  pl32swap(c1, c3);
        pl32swap(c4, c6);  pl32swap(c5, c7);
        uint4 B0, B1;                 // P^T B-frags, k-windows 0-15 / 16-31
        B0.x = c0; B0.y = c1; B0.z = c2; B0.w = c3;
        B1.x = c4; B1.y = c5; B1.z = c6; B1.w = c7;
        const short8 pb0 = __builtin_bit_cast(short8, B0);
        const short8 pb1 = __builtin_bit_cast(short8, B1);
        __builtin_amdgcn_s_setprio(1);
        O0 = MFMA32x16(vf[0], pb0, O0, 0, 0, 0);
        O0 = MFMA32x16(vf[1], pb1, O0, 0, 0, 0);
        O1 = MFMA32x16(vf[2], pb0, O1, 0, 0, 0);
        O1 = MFMA32x16(vf[3], pb1, O1, 0, 0, 0);
        __builtin_amdgcn_s_setprio(0);
    };

    short8 kf[4], vf[4];
    load_k(kf, 0);
    load_v(vf, 0);
    f32x16 svA, svB;

#pragma unroll 1
    for (int t = 0; t < cnt; ++t) {
        qk_nt(svA, kf, qf[0]);                        // S(t,0)
        tail_nt(svA, vf, lpa[0], O[0][0], O[1][0]);   // (t,0): vf slack = QK+exp
        qk_nt(svB, kf, qf[1]);                        // S(t,1) -- last use of kf
        load_k(kf, t + 1);                            // K slack ~= tail_nt (~400cy)
        __builtin_amdgcn_sched_barrier(0);
        tail_nt(svB, vf, lpa[1], O[0][1], O[1][1]);   // (t,1) -- last use of vf
        load_v(vf, t + 1);                            // V slack ~= next QK+exp
        __builtin_amdgcn_sched_barrier(0);
    }

    // ---- epilogue (R17-proven) ----
    // combine lp halves (disjoint token sets), lane (c31,*) -> lp[qrow nt*32+c31]
#pragma unroll
    for (int nt = 0; nt < 2; ++nt) lpa[nt] += __shfl_xor(lpa[nt], 32);

    float* lpbuf = (float*)(smem + 87040);
    if (hw == 0) {
#pragma unroll
        for (int nt = 0; nt < 2; ++nt)
            lpbuf[(h * 6 + s) * 64 + nt * 32 + c31] = lpa[nt];
    }
    if (s != 0) {                          // bf16 O-partial sections
        u16* sec = (u16*)smem + (h * 5 + s - 1) * 4352;
#pragma unroll
        for (int mt = 0; mt < 2; ++mt)
#pragma unroll
            for (int nt = 0; nt < 2; ++nt)
#pragma unroll
                for (int r = 0; r < 16; ++r) {
                    const int ch = mt * 32 + (r & 3) + 8 * (r >> 2) + 4 * hw;
                    sec[(nt * 32 + c31) * 68 + ch] = f2bf(O[mt][nt][r]);
                }
    }
    __syncthreads();   // B2: all partials visible

    float rinv[2];
    if (s == 0) {
#pragma unroll
        for (int nt = 0; nt < 2; ++nt) {
            float sum = 0.f;
#pragma unroll
            for (int sx = 0; sx < 6; ++sx)
                sum += lpbuf[(h * 6 + sx) * 64 + nt * 32 + c31];
            rinv[nt] = 1.0f / sum;
        }
#pragma unroll 1
        for (int sx = 1; sx < 6; ++sx) {
            const u16* sec = (const u16*)smem + (h * 5 + sx - 1) * 4352;
#pragma unroll
            for (int mt = 0; mt < 2; ++mt)
#pragma unroll
                for (int nt = 0; nt < 2; ++nt)
#pragma unroll
                    for (int r = 0; r < 16; ++r) {
                        const int ch = mt * 32 + (r & 3) + 8 * (r >> 2) + 4 * hw;
                        O[mt][nt][r] += bf2f(sec[(nt * 32 + c31) * 68 + ch]);
                    }
        }
    }
    // waves 0-7: convert wm -> bf16 B-frags + bias (overlaps the s==0 reduction)
    short8 wB[4][2];
    float bb[4];
    if (wave < 8) {
#pragma unroll
        for (int nt = 0; nt < 4; ++nt) {
            const int d = nt * 16 + l15;
            const float* wr = wm + (size_t)d * 64 + quad * 8;
            const float4 a0 = *(const float4*)(wr);
            const float4 a1 = *(const float4*)(wr + 4);
            const float4 c0 = *(const float4*)(wr + 32);
            const float4 c1 = *(const float4*)(wr + 36);
            ((u32*)&wB[nt][0])[0] = (u32)f2bf(a0.x) | ((u32)f2bf(a0.y) << 16);
            ((u32*)&wB[nt][0])[1] = (u32)f2bf(a0.z) | ((u32)f2bf(a0.w) << 16);
            ((u32*)&wB[nt][0])[2] = (u32)f2bf(a1.x) | ((u32)f2bf(a1.y) << 16);
            ((u32*)&wB[nt][0])[3] = (u32)f2bf(a1.z) | ((u32)f2bf(a1.w) << 16);
            ((u32*)&wB[nt][1])[0] = (u32)f2bf(c0.x) | ((u32)f2bf(c0.y) << 16);
            ((u32*)&wB[nt][1])[1] = (u32)f2bf(c0.z) | ((u32)f2bf(c0.w) << 16);
            ((u32*)&wB[nt][1])[2] = (u32)f2bf(c1.x) | ((u32)f2bf(c1.y) << 16);
            ((u32*)&wB[nt][1])[3] = (u32)f2bf(c1.z) | ((u32)f2bf(c1.w) << 16);
            bb[nt] = bm[d];
        }
    }
    __syncthreads();   // B3: section/lp reads done; M0 may overlay

    if (s == 0) {      // normalize -> M0 bf16 (swizzled [qrow][ch]) at h*8KB
        u16* M0 = (u16*)smem + h * 4096;
#pragma unroll
        for (int mt = 0; mt < 2; ++mt)
#pragma unroll
            for (int nt = 0; nt < 2; ++nt)
#pragma unroll
                for (int r = 0; r < 16; ++r) {
                    const int lr = nt * 32 + c31;
                    const int ch = mt * 32 + (r & 3) + 8 * (r >> 2) + 4 * hw;
                    const float v = O[mt][nt][r] * rinv[nt];
                    M0[lr * 64 + (((ch >> 3) ^ (lr & 7)) & 7) * 8 + (ch & 7)] = f2bf(v);
                }
    }
    __syncthreads();   // B4: M0 complete

    // mix: wave w<8 handles rows [16w, 16w+16) (R7-proven mapping)
    if (wave < 8) {
        const u16* M0r = (const u16*)smem + (wave >> 2) * 4096;
        const int lr = (wave & 3) * 16 + l15;
        const short8 af0 = *(const short8*)&M0r[lr * 64 + ((quad ^ (lr & 7)) & 7) * 8];
        const short8 af1 = *(const short8*)&M0r[lr * 64 + (((4 + quad) ^ (lr & 7)) & 7) * 8];
        float* Mf = (float*)(smem + 16384);      // [128][68] fp32, disjoint from M0
#pragma unroll
        for (int nt = 0; nt < 4; ++nt) {
            f32x4 acc = {0.f, 0.f, 0.f, 0.f};
            acc = MFMA16x32(af0, wB[nt][0], acc, 0, 0, 0);
            acc = MFMA16x32(af1, wB[nt][1], acc, 0, 0, 0);
#pragma unroll
            for (int r = 0; r < 4; ++r) {
                float v = acc[r] + bb[nt];
                v = v > 0.f ? v : 0.f;
                Mf[(wave * 16 + quad * 4 + r) * 68 + nt * 16 + l15] = v;
            }
        }
    }
    __syncthreads();   // B5

    // 2x2 avg pool (== bilinear 2x downsample, half-pixel); threads 0-511, 4 ch
    if (tid < 512) {
        const float* Mf = (const float*)(smem + 16384);
        const int ow = tid & 31;
        const int cb = (tid >> 5) & 15;
#pragma unroll
        for (int i = 0; i < 4; ++i) {
            const int c = cb + i * 16;
            const float v = 0.25f * (Mf[(2 * ow) * 68 + c] + Mf[(2 * ow + 1) * 68 + c]
                                   + Mf[(64 + 2 * ow) * 68 + c] + Mf[(65 + 2 * ow) * 68 + c]);
            out[((size_t)(b * 64 + c) * 32 + oh) * 32 + ow] = v;
        }
    }
}

extern "C" void kernel_launch(void* const* d_in, const int* in_sizes, int n_in,
                              void* d_out, int out_size, void* d_ws, size_t ws_size,
                              hipStream_t stream) {
    (void)in_sizes; (void)n_in; (void)out_size; (void)ws_size;
    const float* x  = (const float*)d_in[0];
    const float* wq = (const float*)d_in[1];
    const float* bq = (const float*)d_in[2];
    const float* wk = (const float*)d_in[3];
    const float* bk = (const float*)d_in[4];
    const float* wv = (const float*)d_in[5];
    const float* bv = (const float*)d_in[6];
    const float* wm = (const float*)d_in[7];
    const float* bm = (const float*)d_in[8];

    // ws: Q bf16 [8][4096][64] | KF bf16 [8][128][4][512] | VF bf16 [8][128][4][512] = 12 MB
    u16* Q  = (u16*)d_ws;
    u16* KF = Q + (size_t)8 * NTOK * 64;
    u16* VF = KF + (size_t)8 * NTOK * 64;

    qkv_mfma5<<<512, 256, 0, stream>>>(x, wq, bq, wk, bk, wv, bv, Q, KF, VF);
    attn18<<<256, 768, 0, stream>>>(Q, KF, VF, wm, bm, (float*)d_out);
}

// Round 13
// 121.350 us; speedup vs baseline: 1.5455x; 1.0294x over previous
//
#include <hip/hip_runtime.h>
#include <stdint.h>

typedef unsigned short u16;
typedef unsigned int   u32;
typedef __attribute__((ext_vector_type(8)))  short short8;
typedef __attribute__((ext_vector_type(2)))  float f32x2;
typedef __attribute__((ext_vector_type(4)))  float f32x4;
typedef __attribute__((ext_vector_type(16))) float f32x16;

#define NTOK 4096
#define LOG2E 1.44269504088896340736f
#define QS    (0.125f * LOG2E)

// round-to-nearest-even f32 -> bf16
__device__ __forceinline__ u16 f2bf(float f) {
    u32 u = __builtin_bit_cast(u32, f);
    u += 0x7fffu + ((u >> 16) & 1u);
    return (u16)(u >> 16);
}
__device__ __forceinline__ float bf2f(u16 v) {
    return __builtin_bit_cast(float, (u32)v << 16);
}
// gfx950 packed f32->bf16 convert (RNE), 1 VALU op: {lo: bf16(a), hi: bf16(b)}
__device__ __forceinline__ u32 cvtpk(float a, float b) {
    u32 r;
    asm("v_cvt_pk_bf16_f32 %0, %1, %2" : "=v"(r) : "v"(a), "v"(b));
    return r;
}
// gfx950 cross-half swap (VALU, no LDS pipe): after call,
// a = {a.lanes0-31, b.lanes0-31}, b = {a.lanes32-63, b.lanes32-63}
__device__ __forceinline__ void pl32swap(u32 &a, u32 &b) {
    asm("v_permlane32_swap_b32 %0, %1" : "+v"(a), "+v"(b));
}
__device__ __forceinline__ f32x16 zero16() {
    f32x16 v;
#pragma unroll
    for (int i = 0; i < 16; ++i) v[i] = 0.f;
    return v;
}

#define MFMA16x32 __builtin_amdgcn_mfma_f32_16x16x32_bf16
#define MFMA32x16 __builtin_amdgcn_mfma_f32_32x32x16_bf16

// ---------------- kernel 1: QKV projection via MFMA (frozen from R12) ----------------
// K and V stored FRAG-PACKED: every attn fragment load is a contiguous 1KB
// wave load (16 L2 line-requests, minimum) -- R12 proved this is worth 1.3x.
__global__ __launch_bounds__(256) void qkv_mfma5(
    const float* __restrict__ x,
    const float* __restrict__ wq, const float* __restrict__ bq,
    const float* __restrict__ wk, const float* __restrict__ bk,
    const float* __restrict__ wv, const float* __restrict__ bv,
    u16* __restrict__ Q, u16* __restrict__ KF, u16* __restrict__ VF)
{
    __shared__ __align__(16) u16 Wl[3 * 64 * 72];
    __shared__ __align__(16) u16 Xl[64 * 64];
    const int tid  = threadIdx.x;
    const int b    = blockIdx.x & 7;
    const int slab = blockIdx.x >> 3;
    const int n0   = slab << 6;
    const int wave = tid >> 6;
    const int lane = tid & 63;
    const int quad = lane >> 4;
    const int l15  = lane & 15;

#pragma unroll
    for (int j = 0; j < 12; ++j) {
        const float* src = (j < 4) ? wq : (j < 8) ? wk : wv;
        const float sc = (j < 4) ? QS : 1.0f;
        const int idx = (j & 3) * 1024 + tid * 4;
        const float4 v = *(const float4*)(src + idx);
        uint2 pk;
        pk.x = (u32)f2bf(v.x * sc) | ((u32)f2bf(v.y * sc) << 16);
        pk.y = (u32)f2bf(v.z * sc) | ((u32)f2bf(v.w * sc) << 16);
        *(uint2*)&Wl[(j >> 2) * 4608 + (idx >> 6) * 72 + (idx & 63)] = pk;
    }

    float4 xs[4];
#pragma unroll
    for (int g = 0; g < 4; ++g) {
        const int ch = g * 16 + wave * 4 + quad;
        xs[g] = *(const float4*)(x + ((size_t)(b * 64 + ch)) * NTOK + n0 + l15 * 4);
    }
#pragma unroll
    for (int g = 0; g < 4; ++g) {
        const int ch = g * 16 + wave * 4 + quad;
        const float vv[4] = {xs[g].x, xs[g].y, xs[g].z, xs[g].w};
#pragma unroll
        for (int e = 0; e < 4; ++e) {
            const int tok = l15 * 4 + e;
            Xl[tok * 64 + (((ch >> 3) ^ (tok & 7)) & 7) * 8 + (ch & 7)] = f2bf(vv[e]);
        }
    }
    __syncthreads();

    const int row0 = wave * 16 + l15;
    short8 xf[2];
#pragma unroll
    for (int kk = 0; kk < 2; ++kk)
        xf[kk] = *(const short8*)&Xl[row0 * 64 + (((kk * 4 + quad) ^ (row0 & 7)) & 7) * 8];

    const size_t tokbase = (size_t)b * NTOK + n0 + wave * 16;

#pragma unroll
    for (int mat = 0; mat < 2; ++mat) {
        const float* bias = (mat == 0) ? bq : bk;
        const float bsc = (mat == 0) ? QS : 1.0f;
#pragma unroll
        for (int mt = 0; mt < 4; ++mt) {
            const u16* wr = &Wl[mat * 4608 + (mt * 16 + l15) * 72 + quad * 8];
            const short8 wf0 = *(const short8*)(wr);
            const short8 wf1 = *(const short8*)(wr + 32);
            f32x4 acc = {0.f, 0.f, 0.f, 0.f};
            acc = MFMA16x32(wf0, xf[0], acc, 0, 0, 0);
            acc = MFMA16x32(wf1, xf[1], acc, 0, 0, 0);
            const float4 b4 = *(const float4*)(bias + mt * 16 + quad * 4);
            uint2 pk;
            pk.x = (u32)f2bf(acc[0] + b4.x * bsc) | ((u32)f2bf(acc[1] + b4.y * bsc) << 16);
            pk.y = (u32)f2bf(acc[2] + b4.z * bsc) | ((u32)f2bf(acc[3] + b4.w * bsc) << 16);
            if (mat == 0) {
                *(uint2*)(Q + (tokbase + l15) * 64 + mt * 16 + quad * 4) = pk;
            } else {
                const int tokl = wave * 16 + l15;
                const int gt   = slab * 2 + (tokl >> 5);
                const int c31k = tokl & 31;
                const int hwk  = quad >> 1;
                const int j0   = (quad & 1) * 4;
                *(uint2*)(KF + (((size_t)b * 128 + gt) * 4 + mt) * 512
                             + (hwk * 32 + c31k) * 8 + j0) = pk;
            }
        }
    }

    __syncthreads();
    u16* Vl = Xl;
    const int tok = wave * 16 + l15;
#pragma unroll
    for (int mt = 0; mt < 4; ++mt) {
        const u16* wr = &Wl[2 * 4608 + (mt * 16 + l15) * 72 + quad * 8];
        const short8 wf0 = *(const short8*)(wr);
        const short8 wf1 = *(const short8*)(wr + 32);
        f32x4 acc = {0.f, 0.f, 0.f, 0.f};
        acc = MFMA16x32(wf0, xf[0], acc, 0, 0, 0);
        acc = MFMA16x32(wf1, xf[1], acc, 0, 0, 0);
        const float4 b4 = *(const float4*)(bv + mt * 16 + quad * 4);
        const float o[4] = {acc[0] + b4.x, acc[1] + b4.y, acc[2] + b4.z, acc[3] + b4.w};
#pragma unroll
        for (int r = 0; r < 4; ++r) {
            const int d = mt * 16 + quad * 4 + r;
            Vl[d * 64 + (((tok >> 3) ^ ((d >> 1) & 7)) & 7) * 8 + (tok & 7)] = f2bf(o[r]);
        }
    }
    __syncthreads();

#pragma unroll
    for (int dd = 0; dd < 4; ++dd) {
        const int d2   = (tid >> 4) + dd * 16;
        const int tok0 = (tid & 15) * 4;
        const int slot = ((tok0 >> 3) ^ ((d2 >> 1) & 7)) & 7;
        const uint2 v2 = *(const uint2*)&Vl[d2 * 64 + slot * 8 + (tok0 & 7)];
        const int gt  = slab * 2 + (tok0 >> 5);
        const int mk  = ((d2 >> 5) << 1) | ((tok0 & 31) >> 4);
        const int hwv = (tok0 >> 3) & 1;
        const int j   = tok0 & 7;
        *(uint2*)(VF + (((size_t)b * 128 + gt) * 4 + mk) * 512
                     + (hwv * 32 + (d2 & 31)) * 8 + j) = v2;
    }
}

// ---------------- kernel 2: fused attention + mix + 2x2 pool ----------------
// R19 = R14 (best bench: 121.4us, attn 49.0) with ALL s_setprio REMOVED --
// single-variable A/B. Rationale: setprio entered in R13 BUNDLED with the
// tail-shortening, and R13 regressed +3us vs R12. Catalog: setprio is
// NEGATIVE on same-phase waves (m190 GEMM -14TF) and only pays with wave
// role-split. Our K-loop waves run statistically same-phase; setprio(1) on
// MFMA clusters deprioritizes tail-phase waves -- aligning waves into the
// same phase and SERIALIZING the pipes. The measured timeline supports it:
// VALU-busy (42k cyc) + MFMA-busy (33k) ~= 75k of 116k total, i.e. pipes
// nearly serialized. If setprio was the R13 cost: attn ~45-47us. If null:
// 49us and the variable is isolated. Everything else byte-identical to R14
// (3-deep rotation, frag-packed loads, cvtpk/pl32swap tail, R7 epilogue).
__global__ __launch_bounds__(512, 2) void attn19(
    const u16* __restrict__ Q, const u16* __restrict__ KF,
    const u16* __restrict__ VF,
    const float* __restrict__ wm, const float* __restrict__ bm,
    float* __restrict__ out)
{
    __shared__ __align__(16) char smem[54272];
    const int tid  = threadIdx.x;
    const int wave = tid >> 6;
    const int lane = tid & 63;
    const int c31  = lane & 31;
    const int hw   = lane >> 5;          // half-wave
    const int quad = lane >> 4;
    const int l15  = lane & 15;
    const int h    = wave >> 2;          // Q half (64 rows)
    const int s    = wave & 3;           // KV slice (1024 tokens)
    const int b    = blockIdx.x & 7;
    const int oh   = blockIdx.x >> 3;
    const int n0   = oh * 128;

    // Q B-frags: B[k=ch][n=qrow]: lane (c31,hw) reads Q[qrow=nt*32+c31][ks*16+hw*8+j]
    short8 qf[2][4];
#pragma unroll
    for (int nt = 0; nt < 2; ++nt)
#pragma unroll
        for (int ks = 0; ks < 4; ++ks)
            qf[nt][ks] = *(const short8*)(Q + ((size_t)(b * NTOK + n0 + h * 64 + nt * 32 + c31)) * 64
                                            + ks * 16 + hw * 8);

    const u16* KFb = KF + ((size_t)b * 128 + s * 32) * 2048;
    const u16* VFb = VF + ((size_t)b * 128 + s * 32) * 2048;
    const int l8 = lane * 8;             // u16 offset of this lane's 16B frag chunk

    f32x16 O[2][2];                       // [mt][nt] = O^T tiles, 64 AGPR
#pragma unroll
    for (int mt = 0; mt < 2; ++mt)
#pragma unroll
        for (int nt = 0; nt < 2; ++nt) O[mt][nt] = zero16();
    float lpa[2] = {0.f, 0.f};

    auto load_k = [&](short8 (&kf)[4], int t) {
        const int tc = (t < 32) ? t : 31;
        const u16* kt = KFb + (size_t)tc * 2048;
#pragma unroll
        for (int ks = 0; ks < 4; ++ks)
            kf[ks] = *(const short8*)(kt + ks * 512 + l8);
    };
    auto load_v = [&](short8 (&vf)[4], int t) {
        const int tc = (t < 32) ? t : 31;
        const u16* vt = VFb + (size_t)tc * 2048;
#pragma unroll
        for (int mk = 0; mk < 4; ++mk)
            vf[mk] = *(const short8*)(vt + mk * 512 + l8);
    };

    // one pipeline stage: QK on (kf,vf)'s tile, reload kf<-tnext right after
    // QK (kf free), tail (exp/pack/swap/PV), reload vf<-tnext after PV.
    auto stage = [&](short8 (&kf)[4], short8 (&vf)[4], int tnext) {
        f32x16 sv[2];
#pragma unroll
        for (int nt = 0; nt < 2; ++nt) {
            f32x16 a = zero16();
            a = MFMA32x16(kf[0], qf[nt][0], a, 0, 0, 0);
            a = MFMA32x16(kf[1], qf[nt][1], a, 0, 0, 0);
            a = MFMA32x16(kf[2], qf[nt][2], a, 0, 0, 0);
            a = MFMA32x16(kf[3], qf[nt][3], a, 0, 0, 0);
            sv[nt] = a;
        }
        load_k(kf, tnext);                     // ~2.3 stages of slack
        __builtin_amdgcn_sched_barrier(0);
#pragma unroll
        for (int nt = 0; nt < 2; ++nt) {
            float p[16];
#pragma unroll
            for (int r = 0; r < 16; ++r) p[r] = __builtin_amdgcn_exp2f(sv[nt][r]);
            const f32x2 a0 = {p[0],  p[1]},  a1 = {p[2],  p[3]};
            const f32x2 a2 = {p[4],  p[5]},  a3 = {p[6],  p[7]};
            const f32x2 a4 = {p[8],  p[9]},  a5 = {p[10], p[11]};
            const f32x2 a6 = {p[12], p[13]}, a7 = {p[14], p[15]};
            const f32x2 s0 = a0 + a1, s1 = a2 + a3, s2 = a4 + a5, s3 = a6 + a7;
            const f32x2 s4 = s0 + s1, s5 = s2 + s3;
            const f32x2 s6 = s4 + s5;
            lpa[nt] += s6.x + s6.y;
            u32 c0 = cvtpk(p[0],  p[1]),  c1 = cvtpk(p[2],  p[3]);
            u32 c2 = cvtpk(p[4],  p[5]),  c3 = cvtpk(p[6],  p[7]);
            u32 c4 = cvtpk(p[8],  p[9]),  c5 = cvtpk(p[10], p[11]);
            u32 c6 = cvtpk(p[12], p[13]), c7 = cvtpk(p[14], p[15]);
            pl32swap(c0, c2);  pl32swap(c1, c3);
            pl32swap(c4, c6);  pl32swap(c5, c7);
            uint4 B0, B1;                 // P^T B-frags, k-windows 0-15 / 16-31
            B0.x = c0; B0.y = c1; B0.z = c2; B0.w = c3;
            B1.x = c4; B1.y = c5; B1.z = c6; B1.w = c7;
            const short8 pb0 = __builtin_bit_cast(short8, B0);
            const short8 pb1 = __builtin_bit_cast(short8, B1);
            O[0][nt] = MFMA32x16(vf[0], pb0, O[0][nt], 0, 0, 0);
            O[0][nt] = MFMA32x16(vf[1], pb1, O[0][nt], 0, 0, 0);
            O[1][nt] = MFMA32x16(vf[2], pb0, O[1][nt], 0, 0, 0);
            O[1][nt] = MFMA32x16(vf[3], pb1, O[1][nt], 0, 0, 0);
        }
        load_v(vf, tnext);                     // ~2 stages of slack
        __builtin_amdgcn_sched_barrier(0);
    };

    short8 kf0[4], vf0[4], kf1[4], vf1[4], kf2[4], vf2[4];
    load_k(kf0, 0); load_v(vf0, 0);
    load_k(kf1, 1); load_v(vf1, 1);
    load_k(kf2, 2); load_v(vf2, 2);

#pragma unroll 1
    for (int tt = 0; tt < 10; ++tt) {
        const int t0 = tt * 3;
        stage(kf0, vf0, t0 + 3);
        stage(kf1, vf1, t0 + 4);
        stage(kf2, vf2, t0 + 5);
    }
    stage(kf0, vf0, 31);   // tile 30 (prefetch clamped, unused)
    stage(kf1, vf1, 31);   // tile 31 (prefetch clamped, unused)

    // ---- epilogue ----
    // combine lp halves (disjoint token sets), lane (c31,*) -> lp[qrow nt*32+c31]
#pragma unroll
    for (int nt = 0; nt < 2; ++nt) lpa[nt] += __shfl_xor(lpa[nt], 32);

    float* lpbuf = (float*)(smem + 52224);
    if (hw == 0) {
#pragma unroll
        for (int nt = 0; nt < 2; ++nt)
            lpbuf[(h * 4 + s) * 64 + nt * 32 + c31] = lpa[nt];
    }
    if (s != 0) {                          // bf16 O-partial sections
        u16* sec = (u16*)smem + (h * 3 + s - 1) * 4352;
#pragma unroll
        for (int mt = 0; mt < 2; ++mt)
#pragma unroll
            for (int nt = 0; nt < 2; ++nt)
#pragma unroll
                for (int r = 0; r < 16; ++r) {
                    const int ch = mt * 32 + (r & 3) + 8 * (r >> 2) + 4 * hw;
                    sec[(nt * 32 + c31) * 68 + ch] = f2bf(O[mt][nt][r]);
                }
    }
    __syncthreads();   // B2: all partials visible

    float rinv[2];
    if (s == 0) {
#pragma unroll
        for (int nt = 0; nt < 2; ++nt) {
            float sum = 0.f;
#pragma unroll
            for (int sx = 0; sx < 4; ++sx)
                sum += lpbuf[(h * 4 + sx) * 64 + nt * 32 + c31];
            rinv[nt] = 1.0f / sum;
        }
#pragma unroll
        for (int sx = 1; sx < 4; ++sx) {
            const u16* sec = (const u16*)smem + (h * 3 + sx - 1) * 4352;
#pragma unroll
            for (int mt = 0; mt < 2; ++mt)
#pragma unroll
                for (int nt = 0; nt < 2; ++nt)
#pragma unroll
                    for (int r = 0; r < 16; ++r) {
                        const int ch = mt * 32 + (r & 3) + 8 * (r >> 2) + 4 * hw;
                        O[mt][nt][r] += bf2f(sec[(nt * 32 + c31) * 68 + ch]);
                    }
        }
    }
    // all waves: convert wm -> bf16 B-frags + bias (global reads, overlaps reduction)
    short8 wB[4][2];
    float bb[4];
#pragma unroll
    for (int nt = 0; nt < 4; ++nt) {
        const int d = nt * 16 + l15;
        const float* wr = wm + (size_t)d * 64 + quad * 8;
        const float4 a0 = *(const float4*)(wr);
        const float4 a1 = *(const float4*)(wr + 4);
        const float4 c0 = *(const float4*)(wr + 32);
        const float4 c1 = *(const float4*)(wr + 36);
        ((u32*)&wB[nt][0])[0] = (u32)f2bf(a0.x) | ((u32)f2bf(a0.y) << 16);
        ((u32*)&wB[nt][0])[1] = (u32)f2bf(a0.z) | ((u32)f2bf(a0.w) << 16);
        ((u32*)&wB[nt][0])[2] = (u32)f2bf(a1.x) | ((u32)f2bf(a1.y) << 16);
        ((u32*)&wB[nt][0])[3] = (u32)f2bf(a1.z) | ((u32)f2bf(a1.w) << 16);
        ((u32*)&wB[nt][1])[0] = (u32)f2bf(c0.x) | ((u32)f2bf(c0.y) << 16);
        ((u32*)&wB[nt][1])[1] = (u32)f2bf(c0.z) | ((u32)f2bf(c0.w) << 16);
        ((u32*)&wB[nt][1])[2] = (u32)f2bf(c1.x) | ((u32)f2bf(c1.y) << 16);
        ((u32*)&wB[nt][1])[3] = (u32)f2bf(c1.z) | ((u32)f2bf(c1.w) << 16);
        bb[nt] = bm[d];
    }
    __syncthreads();   // B3: section reads done; M0 may overlay

    if (s == 0) {      // normalize -> M0 bf16 (swizzled [qrow][ch]) at h*8KB
        u16* M0 = (u16*)smem + h * 4096;
#pragma unroll
        for (int mt = 0; mt < 2; ++mt)
#pragma unroll
            for (int nt = 0; nt < 2; ++nt)
#pragma unroll
                for (int r = 0; r < 16; ++r) {
                    const int lr = nt * 32 + c31;
                    const int ch = mt * 32 + (r & 3) + 8 * (r >> 2) + 4 * hw;
                    const float v = O[mt][nt][r] * rinv[nt];
                    M0[lr * 64 + (((ch >> 3) ^ (lr & 7)) & 7) * 8 + (ch & 7)] = f2bf(v);
                }
    }
    __syncthreads();   // B4

    // mix: wave w handles rows [16w, 16w+16) (R7-proven)
    const u16* M0r = (const u16*)smem + (wave >> 2) * 4096;
    const int lr = (wave & 3) * 16 + l15;
    const short8 af0 = *(const short8*)&M0r[lr * 64 + ((quad ^ (lr & 7)) & 7) * 8];
    const short8 af1 = *(const short8*)&M0r[lr * 64 + (((4 + quad) ^ (lr & 7)) & 7) * 8];
    float* Mf = (float*)(smem + 16384);      // [128][68] fp32, disjoint from M0
#pragma unroll
    for (int nt = 0; nt < 4; ++nt) {
        f32x4 acc = {0.f, 0.f, 0.f, 0.f};
        acc = MFMA16x32(af0, wB[nt][0], acc, 0, 0, 0);
        acc = MFMA16x32(af1, wB[nt][1], acc, 0, 0, 0);
#pragma unroll
        for (int r = 0; r < 4; ++r) {
            float v = acc[r] + bb[nt];
            v = v > 0.f ? v : 0.f;
            Mf[(wave * 16 + quad * 4 + r) * 68 + nt * 16 + l15] = v;
        }
    }
    __syncthreads();   // B5

    // 2x2 avg pool (== bilinear 2x downsample, half-pixel)
    const int ow = tid & 31;
    const int cb = (tid >> 5) & 15;
#pragma unroll
    for (int i = 0; i < 4; ++i) {
        const int c = cb + i * 16;
        const float v = 0.25f * (Mf[(2 * ow) * 68 + c] + Mf[(2 * ow + 1) * 68 + c]
                               + Mf[(64 + 2 * ow) * 68 + c] + Mf[(65 + 2 * ow) * 68 + c]);
        out[((size_t)(b * 64 + c) * 32 + oh) * 32 + ow] = v;
    }
}

extern "C" void kernel_launch(void* const* d_in, const int* in_sizes, int n_in,
                              void* d_out, int out_size, void* d_ws, size_t ws_size,
                              hipStream_t stream) {
    (void)in_sizes; (void)n_in; (void)out_size; (void)ws_size;
    const float* x  = (const float*)d_in[0];
    const float* wq = (const float*)d_in[1];
    const float* bq = (const float*)d_in[2];
    const float* wk = (const float*)d_in[3];
    const float* bk = (const float*)d_in[4];
    const float* wv = (const float*)d_in[5];
    const float* bv = (const float*)d_in[6];
    const float* wm = (const float*)d_in[7];
    const float* bm = (const float*)d_in[8];

    // ws: Q bf16 [8][4096][64] | KF bf16 [8][128][4][512] | VF bf16 [8][128][4][512] = 12 MB
    u16* Q  = (u16*)d_ws;
    u16* KF = Q + (size_t)8 * NTOK * 64;
    u16* VF = KF + (size_t)8 * NTOK * 64;

    qkv_mfma5<<<512, 256, 0, stream>>>(x, wq, bq, wk, bk, wv, bv, Q, KF, VF);
    attn19<<<256, 512, 0, stream>>>(Q, KF, VF, wm, bm, (float*)d_out);
}